// Round 10
// baseline (346.348 us; speedup 1.0000x reference)
//
#include <hip/hip_runtime.h>
#include <math.h>

#define BB 512
#define TT 1024
#define NS 50

typedef _Float16 half2_t __attribute__((ext_vector_type(2)));

static __device__ __forceinline__ half2_t pk_h2(float a, float b) {
    auto r = __builtin_amdgcn_cvt_pkrtz(a, b);
    return __builtin_bit_cast(half2_t, r);
}
static __device__ __forceinline__ float wave_sum_f(float v) {
    #pragma unroll
    for (int k = 32; k >= 1; k >>= 1) v += __shfl_xor(v, k, 64);
    return v;
}
static __device__ __forceinline__ int wave_sum_i(int v) {
    #pragma unroll
    for (int k = 32; k >= 1; k >>= 1) v += __shfl_xor(v, k, 64);
    return v;
}
#define FDOT(a, b, c) __builtin_amdgcn_fdot2((a), (b), (c), false)
#define H2F(x) __builtin_bit_cast(half2_t, (x))

// ---- one chain half-step ----------------------------------------------------
// Consumes broadcast regs P0..P6 (p(k), loaded LAST iter), produces u(k+1),
// packs+writes p(k+1) to BUF, issues reads for NEXT iter back into P0..P6.
// The ds_read latency is covered by the OTHER chain's half-step.
#define HALF(u, rr, kp, K, E, BUF, P0, P1, P2, P3, P4, P5, P6, eexp) do {     \
    K += kp;                                                                  \
    float s0_=0.f,s1_=0.f,s2_=0.f,s3_=0.f,s4_=0.f,s5_=0.f,s6_=0.f,s7_=0.f;    \
    s0_=FDOT(H2F(P0.x),E##0, s0_); s1_=FDOT(H2F(P0.y),E##1, s1_);             \
    s2_=FDOT(H2F(P0.z),E##2, s2_); s3_=FDOT(H2F(P0.w),E##3, s3_);             \
    s4_=FDOT(H2F(P1.x),E##4, s4_); s5_=FDOT(H2F(P1.y),E##5, s5_);             \
    s6_=FDOT(H2F(P1.z),E##6, s6_); s7_=FDOT(H2F(P1.w),E##7, s7_);             \
    s0_=FDOT(H2F(P2.x),E##8, s0_); s1_=FDOT(H2F(P2.y),E##9, s1_);             \
    s2_=FDOT(H2F(P2.z),E##10,s2_); s3_=FDOT(H2F(P2.w),E##11,s3_);             \
    s4_=FDOT(H2F(P3.x),E##12,s4_); s5_=FDOT(H2F(P3.y),E##13,s5_);             \
    s6_=FDOT(H2F(P3.z),E##14,s6_); s7_=FDOT(H2F(P3.w),E##15,s7_);             \
    s0_=FDOT(H2F(P4.x),E##16,s0_); s1_=FDOT(H2F(P4.y),E##17,s1_);             \
    s2_=FDOT(H2F(P4.z),E##18,s2_); s3_=FDOT(H2F(P4.w),E##19,s3_);             \
    s4_=FDOT(H2F(P5.x),E##20,s4_); s5_=FDOT(H2F(P5.y),E##21,s5_);             \
    s6_=FDOT(H2F(P5.z),E##22,s6_); s7_=FDOT(H2F(P5.w),E##23,s7_);             \
    s0_=FDOT(H2F(P6.x),E##24,s0_);                                            \
    float S_=((s0_+s1_)+(s2_+s3_))+((s4_+s5_)+(s6_+s7_));                     \
    (u)=S_*(eexp);                                                            \
    int bb_=__builtin_amdgcn_readlane(__float_as_int(u),7);                   \
    (kp)=((bb_>>23)&255)-127; (rr)=(127-(kp))<<23;                            \
    float p_=(u)*__int_as_float(rr);                                          \
    int pn_=__builtin_amdgcn_update_dpp(__float_as_int(p_),                   \
              __float_as_int(p_),0xB1,0xF,0xF,true);                          \
    float pnf_=__int_as_float(pn_);                                           \
    float lo_=(lane&1)?pnf_:p_, hi_=(lane&1)?p_:pnf_;                         \
    BUF[lane>>1]=__builtin_bit_cast(float,pk_h2(lo_,hi_));                    \
    const float4* m4_=(const float4*)(BUF);                                   \
    P0=m4_[0]; P1=m4_[1]; P2=m4_[2]; P3=m4_[3];                               \
    P4=m4_[4]; P5=m4_[5]; P6=m4_[6];                                          \
} while (0)

// prime: set kp/rr from u, pack+write p(0), preload P0..P6
#define PRIME(u, rr, kp, BUF, P0, P1, P2, P3, P4, P5, P6) do {                \
    int bb_=__builtin_amdgcn_readlane(__float_as_int(u),7);                   \
    (kp)=((bb_>>23)&255)-127; (rr)=(127-(kp))<<23;                            \
    float p_=(u)*__int_as_float(rr);                                          \
    int pn_=__builtin_amdgcn_update_dpp(__float_as_int(p_),                   \
              __float_as_int(p_),0xB1,0xF,0xF,true);                          \
    float pnf_=__int_as_float(pn_);                                           \
    float lo_=(lane&1)?pnf_:p_, hi_=(lane&1)?p_:pnf_;                         \
    BUF[lane>>1]=__builtin_bit_cast(float,pk_h2(lo_,hi_));                    \
    const float4* m4_=(const float4*)(BUF);                                   \
    P0=m4_[0]; P1=m4_[1]; P2=m4_[2]; P3=m4_[3];                               \
    P4=m4_[4]; P5=m4_[5]; P6=m4_[6];                                          \
} while (0)

#define HALF_F(eexp) HALF(uf, rrf, kpf, Kf, ef, bufF, cf0,cf1,cf2,cf3,cf4,cf5,cf6, eexp)
#define HALF_B(eexp) HALF(ub, rrb, kpb, Kb, eb, bufB, cb0,cb1,cb2,cb3,cb4,cb5,cb6, eexp)

__global__ __launch_bounds__(64, 1) void crf_nll_kernel(
    const float* __restrict__ feat,    // (B, T, N)
    const float* __restrict__ trans,   // (N, N)
    const int*   __restrict__ tags,    // (B, T)
    const int*   __restrict__ mask,    // (B, T)
    float* __restrict__ out)           // (B,)
{
    const int b    = blockIdx.x;
    const int lane = threadIdx.x;      // lane == state j
    const int jj   = (lane < NS) ? lane : 0;

    __shared__ __align__(16) float bufF[32];
    __shared__ __align__(16) float bufB[32];

    // --- E fragments, both orientations, named regs.
    // fwd: ef_m = (E[2m][j], E[2m+1][j]);  bwd: eb_m = (E[j][2m], E[j][2m+1])
    // exp(-10000) == 0 exactly -> forbidden transitions vanish.
#define INIT_EF(m) half2_t ef##m; { \
        float x0=__expf(trans[(2*(m)+0)*NS+jj]); \
        float x1=__expf(trans[(2*(m)+1)*NS+jj]); \
        if (lane>=NS){x0=0.f;x1=0.f;} ef##m=pk_h2(x0,x1); }
#define INIT_EB(m) half2_t eb##m; { \
        float x0=__expf(trans[jj*NS+2*(m)+0]); \
        float x1=__expf(trans[jj*NS+2*(m)+1]); \
        if (lane>=NS){x0=0.f;x1=0.f;} eb##m=pk_h2(x0,x1); }
    INIT_EF(0)  INIT_EF(1)  INIT_EF(2)  INIT_EF(3)  INIT_EF(4)
    INIT_EF(5)  INIT_EF(6)  INIT_EF(7)  INIT_EF(8)  INIT_EF(9)
    INIT_EF(10) INIT_EF(11) INIT_EF(12) INIT_EF(13) INIT_EF(14)
    INIT_EF(15) INIT_EF(16) INIT_EF(17) INIT_EF(18) INIT_EF(19)
    INIT_EF(20) INIT_EF(21) INIT_EF(22) INIT_EF(23) INIT_EF(24)
    INIT_EB(0)  INIT_EB(1)  INIT_EB(2)  INIT_EB(3)  INIT_EB(4)
    INIT_EB(5)  INIT_EB(6)  INIT_EB(7)  INIT_EB(8)  INIT_EB(9)
    INIT_EB(10) INIT_EB(11) INIT_EB(12) INIT_EB(13) INIT_EB(14)
    INIT_EB(15) INIT_EB(16) INIT_EB(17) INIT_EB(18) INIT_EB(19)
    INIT_EB(20) INIT_EB(21) INIT_EB(22) INIT_EB(23) INIT_EB(24)
#undef INIT_EF
#undef INIT_EB

    // --- sequence length (mask is a prefix of ones); uniform; len in [512,1024] ---
    int cnt = 0;
    for (int t = lane; t < TT; t += 64) cnt += mask[b * TT + t];
    const int len = wave_sum_i(cnt);
    const int tm  = (len - 1) >> 1;
    const int nf  = tm;                 // fwd steps
    const int nb  = len - 1 - tm;       // bwd steps; nb-nf in {0,1}

    const float* fb = feat + (size_t)b * TT * NS;

    // --- prob-domain init ---
    float uf = (lane < NS) ? __expf(trans[jj] + fb[jj]) : 0.f;
    float ub = (lane < NS) ? __expf(trans[jj*NS+1] + fb[(size_t)(len-1)*NS + jj]) : 0.f;
    int Kf = 0, Kb = 0, kpf, kpb, rrf, rrb;

    float4 cf0, cf1, cf2, cf3, cf4, cf5, cf6;
    float4 cb0, cb1, cb2, cb3, cb4, cb5, cb6;
    PRIME(uf, rrf, kpf, bufF, cf0,cf1,cf2,cf3,cf4,cf5,cf6);
    PRIME(ub, rrb, kpb, bufB, cb0,cb1,cb2,cb3,cb4,cb5,cb6);

    // --- depth-4 prefetch per stream, PRE-EXP'D; len>=512 -> no clamps needed ---
    float qf0 = __expf(fb[(size_t)(1)*NS + jj]);
    float qf1 = __expf(fb[(size_t)(2)*NS + jj]);
    float qf2 = __expf(fb[(size_t)(3)*NS + jj]);
    float qf3 = __expf(fb[(size_t)(4)*NS + jj]);
    float qb0 = __expf(fb[(size_t)(len-2)*NS + jj]);
    float qb1 = __expf(fb[(size_t)(len-3)*NS + jj]);
    float qb2 = __expf(fb[(size_t)(len-4)*NS + jj]);
    float qb3 = __expf(fb[(size_t)(len-5)*NS + jj]);

#define ITER(QF, QB, D) {                                                     \
        float fx_ = QF;                                                       \
        { int tl_ = 1 + k + (D) + 4;                                          \
          QF = __expf(fb[(size_t)tl_ * NS + jj]); }                           \
        HALF_F(fx_);                                                          \
        float bx_ = QB;                                                       \
        { int tl_ = len - 2 - (k + (D) + 4); tl_ = (tl_ < 0) ? 0 : tl_;       \
          QB = __expf(fb[(size_t)tl_ * NS + jj]); }                           \
        HALF_B(bx_);                                                          \
    }

    int k = 0;
    for (; k + 4 <= nf; k += 4) {
        ITER(qf0, qb0, 0)
        ITER(qf1, qb1, 1)
        ITER(qf2, qb2, 2)
        ITER(qf3, qb3, 3)
    }
#undef ITER
    const int d0 = nf - k;   // 0..3 remaining paired iters
    if (d0 > 0) { HALF_F(qf0); HALF_B(qb0); }
    if (d0 > 1) { HALF_F(qf1); HALF_B(qb1); }
    if (d0 > 2) { HALF_F(qf2); HALF_B(qb2); }
    if (nb > nf) {           // one extra bwd step, feature row = tm (pre-exp'd reg)
        float ee = (d0 == 0) ? qb0 : (d0 == 1) ? qb1 : (d0 == 2) ? qb2 : qb3;
        HALF_B(ee);
    }

    // --- combine: log_z = ln(sum_j uf*ub*exp(-feat[tm][j])) + (Kf+Kb)*ln2 ---
    float wv = uf * ub * __expf(-fb[(size_t)tm * NS + jj]);  // dead lanes: uf==0
    float W = wave_sum_f(wv);
    float log_z = __logf(W) + (float)(Kf + Kb) * 0.6931471805599453f;

    // --- gold path score (exact, log-domain), lane-parallel over t ---
    const int* tb = tags + (size_t)b * TT;
    float sc = 0.0f;
    for (int t2 = lane; t2 < len; t2 += 64) {
        int tg = tb[t2];
        sc += fb[(size_t)t2 * NS + tg];
        if (t2 >= 1) sc += trans[tb[t2 - 1] * NS + tg];
    }
    sc = wave_sum_f(sc);

    if (lane == 0) {
        sc += trans[tb[0]]                      // trans[ROOT][tag0]
            + trans[tb[len - 1] * NS + 1];      // trans[tag_last][END]
        out[b] = log_z - sc;
    }
}

extern "C" void kernel_launch(void* const* d_in, const int* in_sizes, int n_in,
                              void* d_out, int out_size, void* d_ws, size_t ws_size,
                              hipStream_t stream) {
    const float* feat  = (const float*)d_in[0];
    const float* trans = (const float*)d_in[1];
    const int*   tags  = (const int*)d_in[2];
    const int*   mask  = (const int*)d_in[3];
    float* out = (float*)d_out;
    crf_nll_kernel<<<dim3(BB), dim3(64), 0, stream>>>(feat, trans, tags, mask, out);
}